// Round 4
// baseline (292.088 us; speedup 1.0000x reference)
//
#include <hip/hip_runtime.h>
#include <hip/hip_bf16.h>

typedef unsigned short u16;
typedef unsigned int u32;

#define HDIM 64
#define EPS 1e-5f

// ---------- helpers ----------

__device__ __forceinline__ float wave_sum64(float v) {
    v += __shfl_xor(v, 1, 64);
    v += __shfl_xor(v, 2, 64);
    v += __shfl_xor(v, 4, 64);
    v += __shfl_xor(v, 8, 64);
    v += __shfl_xor(v, 16, 64);
    v += __shfl_xor(v, 32, 64);
    return v;
}

__device__ __forceinline__ float bcast(float v, int k) {
    return __int_as_float(__builtin_amdgcn_readlane(__float_as_int(v), k));
}

// round-to-nearest-even f32 -> bf16 bits
__device__ __forceinline__ u16 f2bf(float f) {
    u32 u = __float_as_uint(f);
    u32 r = (u + 0x7fffu + ((u >> 16) & 1u)) >> 16;
    return (u16)r;
}

// lane-local layernorm of a 64-float register array.
#define LANE_LN(arr, gptr, bptr) do {                                   \
    float s0_ = 0.f, s1_ = 0.f, s2_ = 0.f, s3_ = 0.f;                   \
    _Pragma("unroll")                                                   \
    for (int k_ = 0; k_ < 64; k_ += 4) {                                \
        s0_ += (arr)[k_]; s1_ += (arr)[k_+1];                           \
        s2_ += (arr)[k_+2]; s3_ += (arr)[k_+3];                         \
    }                                                                   \
    const float mu_ = (s0_ + s1_ + s2_ + s3_) * 0.015625f;              \
    float v0_ = 0.f, v1_ = 0.f, v2_ = 0.f, v3_ = 0.f;                   \
    _Pragma("unroll")                                                   \
    for (int k_ = 0; k_ < 64; k_ += 4) {                                \
        float d0_ = (arr)[k_]   - mu_;  v0_ = fmaf(d0_, d0_, v0_);      \
        float d1_ = (arr)[k_+1] - mu_;  v1_ = fmaf(d1_, d1_, v1_);      \
        float d2_ = (arr)[k_+2] - mu_;  v2_ = fmaf(d2_, d2_, v2_);      \
        float d3_ = (arr)[k_+3] - mu_;  v3_ = fmaf(d3_, d3_, v3_);      \
    }                                                                   \
    const float rs_ = rsqrtf((v0_+v1_+v2_+v3_) * 0.015625f + EPS);      \
    _Pragma("unroll")                                                   \
    for (int k_ = 0; k_ < 64; ++k_)                                     \
        (arr)[k_] = ((arr)[k_] - mu_) * rs_ * (gptr)[k_] + (bptr)[k_];  \
} while (0)

// matmul into acc[] (bias-init by caller): acc[h] += sum_k src[k]*W[k*64+h]
#define MAT_ACC(acc, src, Wlds) do {                                    \
    _Pragma("unroll")                                                   \
    for (int k_ = 0; k_ < 64; ++k_) {                                   \
        const float s_ = (src)[k_];                                     \
        const float4* w_ = (const float4*)&(Wlds)[k_ << 6];             \
        _Pragma("unroll")                                               \
        for (int q_ = 0; q_ < 16; ++q_) {                               \
            float4 u_ = w_[q_];                                         \
            (acc)[4*q_]   = fmaf(s_, u_.x, (acc)[4*q_]);                \
            (acc)[4*q_+1] = fmaf(s_, u_.y, (acc)[4*q_+1]);              \
            (acc)[4*q_+2] = fmaf(s_, u_.z, (acc)[4*q_+2]);              \
            (acc)[4*q_+3] = fmaf(s_, u_.w, (acc)[4*q_+3]);              \
        }                                                               \
    }                                                                   \
} while (0)

// pack 64 floats -> 64 bf16 and store as 8 x uint4
#define PACK_STORE(dst, arr) do {                                       \
    uint4* o_ = (uint4*)(dst);                                          \
    _Pragma("unroll")                                                   \
    for (int q_ = 0; q_ < 8; ++q_) {                                    \
        uint4 w_;                                                       \
        w_.x = (u32)f2bf((arr)[8*q_])   | ((u32)f2bf((arr)[8*q_+1]) << 16); \
        w_.y = (u32)f2bf((arr)[8*q_+2]) | ((u32)f2bf((arr)[8*q_+3]) << 16); \
        w_.z = (u32)f2bf((arr)[8*q_+4]) | ((u32)f2bf((arr)[8*q_+5]) << 16); \
        w_.w = (u32)f2bf((arr)[8*q_+6]) | ((u32)f2bf((arr)[8*q_+7]) << 16); \
        o_[q_] = w_;                                                    \
    }                                                                   \
} while (0)

// ---------- phase 1: per-node transform -> bf16 tables ----------
// Node-per-lane, lifetimes staged so peak live state is 2x64 floats:
//   r=LN(row); a=relu/LN(r@W2+b2) -> store T2; a=relu/LN(r@W1+b1) [r dies];
//   r=a@B -> store T1.   Keeps VGPR < 256 cap (launch_bounds 256,2): no spill.
__global__ __launch_bounds__(256, 2) void phase1_kernel(
    const float* __restrict__ z,
    const float* __restrict__ root_w, const float* __restrict__ root_b,
    const float* __restrict__ lin1_w, const float* __restrict__ lin1_b,
    const float* __restrict__ lin2_w, const float* __restrict__ lin2_b,
    const float* __restrict__ bil_w,
    const float* __restrict__ norm_g, const float* __restrict__ norm_b,
    u16* __restrict__ T1, u16* __restrict__ T2, int nnodes)
{
    // W1t[k*64+h] = lin1_w[h*64+k] (transpose on the global-read side;
    // LDS writes linear, compute reads wave-uniform -> broadcast, no conflicts)
    __shared__ float W1t[4096], W2t[4096], Bs[4096];
    __shared__ float gbuf[64], bbuf[64], b1buf[64], b2buf[64];

    const int tid = threadIdx.x;
    for (int i = tid; i < 4096; i += 256) {
        const int k = i >> 6, h = i & 63;
        W1t[i] = lin1_w[(h << 6) | k];
        W2t[i] = lin2_w[(h << 6) | k];
        Bs[i]  = bil_w[i];               // Bs[h*64+g], row-major as given
    }
    if (tid < 64) {
        gbuf[tid]  = norm_g[tid];
        bbuf[tid]  = norm_b[tid];
        b1buf[tid] = lin1_b[tid];
        b2buf[tid] = lin2_b[tid];
    }
    __syncthreads();

    const int node = blockIdx.x * 256 + tid;
    if (node >= nnodes) return;

    // ---- r = LN(row) ----
    float r[64];
    if (node == 0) {
#pragma unroll
        for (int k = 0; k < 64; ++k) r[k] = root_w[k] + root_b[k];
    } else {
        const float4* zp = (const float4*)(z + (size_t)(node - 1) * HDIM);
#pragma unroll
        for (int q = 0; q < 16; ++q) {
            float4 v = zp[q];
            r[4*q] = v.x; r[4*q+1] = v.y; r[4*q+2] = v.z; r[4*q+3] = v.w;
        }
    }
    LANE_LN(r, gbuf, bbuf);

    float a[64];

    // ---- branch 2 first: a = LN(relu(r@W2 + b2)) -> T2, then a dies ----
#pragma unroll
    for (int h = 0; h < 64; ++h) a[h] = b2buf[h];
    MAT_ACC(a, r, W2t);
#pragma unroll
    for (int h = 0; h < 64; ++h) a[h] = fmaxf(a[h], 0.f);
    LANE_LN(a, gbuf, bbuf);
    PACK_STORE(T2 + (size_t)node * HDIM, a);

    // ---- branch 1: a = LN(relu(r@W1 + b1)); r dies in the k-loop ----
#pragma unroll
    for (int h = 0; h < 64; ++h) a[h] = b1buf[h];
    MAT_ACC(a, r, W1t);
#pragma unroll
    for (int h = 0; h < 64; ++h) a[h] = fmaxf(a[h], 0.f);
    LANE_LN(a, gbuf, bbuf);

    // ---- reuse r as t = a @ B -> T1 ----
#pragma unroll
    for (int g = 0; g < 64; ++g) r[g] = 0.f;
    MAT_ACC(r, a, Bs);
    PACK_STORE(T1 + (size_t)node * HDIM, r);
}

// ---------- phase 2: per-edge gather + 64-dot ----------
__global__ __launch_bounds__(256) void phase2_kernel(
    const int* __restrict__ arcs,
    const u16* __restrict__ T1, const u16* __restrict__ T2,
    const float* __restrict__ bil_b,
    float* __restrict__ out, int E)
{
    const int tid = blockIdx.x * 256 + threadIdx.x;
    const int e = tid >> 3;
    if (e >= E) return;
    const int l8 = tid & 7;

    const int i0 = arcs[2 * e];
    const int i1 = arcs[2 * e + 1];

    const uint4* p1 = (const uint4*)(T1 + (size_t)i0 * HDIM) + l8;
    const uint4* p2 = (const uint4*)(T2 + (size_t)i1 * HDIM) + l8;
    uint4 u = *p1;
    uint4 v = *p2;

    float s = 0.f;
    {
        u32 ua[4] = {u.x, u.y, u.z, u.w};
        u32 va[4] = {v.x, v.y, v.z, v.w};
#pragma unroll
        for (int i = 0; i < 4; ++i) {
            float alo = __uint_as_float(ua[i] << 16);
            float ahi = __uint_as_float(ua[i] & 0xffff0000u);
            float blo = __uint_as_float(va[i] << 16);
            float bhi = __uint_as_float(va[i] & 0xffff0000u);
            s = fmaf(alo, blo, s);
            s = fmaf(ahi, bhi, s);
        }
    }
    s += __shfl_xor(s, 1, 64);
    s += __shfl_xor(s, 2, 64);
    s += __shfl_xor(s, 4, 64);
    if (l8 == 0) out[e] = s + bil_b[0];
}

// ---------- fallback: per-edge full recompute (if ws too small) ----------
__device__ __forceinline__ float lnorm_w(float v, float g, float b) {
    float mu = wave_sum64(v) * 0.015625f;
    float d  = v - mu;
    float var = wave_sum64(d * d) * 0.015625f;
    return d * rsqrtf(var + EPS) * g + b;
}

__global__ __launch_bounds__(256) void edge_direct_kernel(
    const float* __restrict__ z, const int* __restrict__ arcs,
    const float* __restrict__ root_w, const float* __restrict__ root_b,
    const float* __restrict__ lin1_w, const float* __restrict__ lin1_b,
    const float* __restrict__ lin2_w, const float* __restrict__ lin2_b,
    const float* __restrict__ bil_w, const float* __restrict__ bil_b,
    const float* __restrict__ norm_g, const float* __restrict__ norm_b,
    float* __restrict__ out, int E, int nnodes)
{
    __shared__ float W1t[4096], W2t[4096], Bs[4096];
    const int tid = threadIdx.x;
    for (int i = tid; i < 4096; i += 256) {
        int h = i >> 6, k = i & 63;
        W1t[(k << 6) | h] = lin1_w[i];
        W2t[(k << 6) | h] = lin2_w[i];
        Bs[i] = bil_w[i];
    }
    __syncthreads();

    const int lane = tid & 63;
    const float g  = norm_g[lane], bt = norm_b[lane];
    const float b1 = lin1_b[lane], b2 = lin2_b[lane];
    const float rootv = root_w[lane] + root_b[lane];

    const int gwave = (blockIdx.x * 256 + tid) >> 6;
    const int nwaves = (gridDim.x * 256) >> 6;

    for (int e = gwave; e < E; e += nwaves) {
        int i0 = arcs[2 * e], i1 = arcs[2 * e + 1];
        float v0 = (i0 == 0) ? rootv : z[(size_t)(i0 - 1) * HDIM + lane];
        float v1 = (i1 == 0) ? rootv : z[(size_t)(i1 - 1) * HDIM + lane];
        float l0 = lnorm_w(v0, g, bt);
        float l1 = lnorm_w(v1, g, bt);
        float a1 = 0.f, a2 = 0.f;
#pragma unroll
        for (int k = 0; k < 64; ++k) {
            a1 = fmaf(bcast(l0, k), W1t[(k << 6) | lane], a1);
            a2 = fmaf(bcast(l1, k), W2t[(k << 6) | lane], a2);
        }
        float x1 = lnorm_w(fmaxf(a1 + b1, 0.f), g, bt);
        float x2 = lnorm_w(fmaxf(a2 + b2, 0.f), g, bt);
        float w1 = 0.f;
#pragma unroll
        for (int h = 0; h < 64; ++h)
            w1 = fmaf(bcast(x1, h), Bs[(h << 6) | lane], w1);
        float sc = wave_sum64(w1 * x2);
        if (lane == 0) out[e] = sc + bil_b[0];
    }
}

// ---------- launch ----------
extern "C" void kernel_launch(void* const* d_in, const int* in_sizes, int n_in,
                              void* d_out, int out_size, void* d_ws, size_t ws_size,
                              hipStream_t stream) {
    const float* z      = (const float*)d_in[0];
    const int*   arcs   = (const int*)  d_in[1];
    const float* root_w = (const float*)d_in[2];
    const float* root_b = (const float*)d_in[3];
    const float* lin1_w = (const float*)d_in[4];
    const float* lin1_b = (const float*)d_in[5];
    const float* lin2_w = (const float*)d_in[6];
    const float* lin2_b = (const float*)d_in[7];
    const float* bil_w  = (const float*)d_in[8];
    const float* bil_b  = (const float*)d_in[9];
    const float* norm_g = (const float*)d_in[10];
    const float* norm_b = (const float*)d_in[11];
    float* out = (float*)d_out;

    const int E      = in_sizes[1] / 2;
    const int nnodes = in_sizes[0] / HDIM + 1;

    const size_t tbl  = (size_t)nnodes * HDIM * sizeof(u16);
    const size_t need = 2 * tbl;

    if (ws_size >= need) {
        u16* T1 = (u16*)d_ws;
        u16* T2 = (u16*)((char*)d_ws + tbl);

        const int blocks1 = (nnodes + 255) / 256;
        phase1_kernel<<<blocks1, 256, 0, stream>>>(
            z, root_w, root_b, lin1_w, lin1_b, lin2_w, lin2_b,
            bil_w, norm_g, norm_b, T1, T2, nnodes);

        const long long thr2 = (long long)E * 8;
        const int blocks2 = (int)((thr2 + 255) / 256);
        phase2_kernel<<<blocks2, 256, 0, stream>>>(arcs, T1, T2, bil_b, out, E);
    } else {
        edge_direct_kernel<<<8192, 256, 0, stream>>>(
            z, arcs, root_w, root_b, lin1_w, lin1_b, lin2_w, lin2_b,
            bil_w, bil_b, norm_g, norm_b, out, E, nnodes);
    }
}